// Round 8
// baseline (1592.163 us; speedup 1.0000x reference)
//
#include <hip/hip_runtime.h>
#include <hip/hip_bf16.h>

// SwiGLU MLP: out = down( silu(x@Wg^T + bg) * (x@Wu^T + bu) ) + bd
// M=4096 tokens, H=4096, I=11008. fp32 in/out, bf16 MFMA compute.
// GEMM: 256x256 tile, BK=64, 8 waves (2Mx4N, 128x64/wave), 2-deep LDS dbuf,
// FRAGMENT-CONTIGUOUS LDS layout (every ds_read_b128 is linear -> zero bank
// conflicts; matches global_load_lds write pattern; gather done on the global
// source address). 4 drifting phases/tile (16 MFMA each, no intra-tile
// barriers), vmcnt(0)+barrier once per K-tile, XCD-aware bijective swizzle.

#define M_TOK 4096
#define HID   4096
#define INT_  11008

typedef __attribute__((ext_vector_type(8))) short bf16x8;
typedef __attribute__((ext_vector_type(4))) float f32x4;

__device__ __forceinline__ unsigned short f2bf(float f) {
    union { float f; unsigned int u; } a; a.f = f;
    unsigned int u = a.u;
    u += 0x7fff + ((u >> 16) & 1);   // RNE
    return (unsigned short)(u >> 16);
}

__device__ __forceinline__ float bf2f(unsigned short h) {
    union { unsigned int u; float f; } a; a.u = ((unsigned int)h) << 16;
    return a.f;
}

// ---------------- fp32 -> bf16 convert (vectorized, grid-stride) ----------------
__global__ void cvt_f32_bf16(const float* __restrict__ in, unsigned short* __restrict__ out, int n4) {
    int stride = gridDim.x * blockDim.x;
    for (int i = blockIdx.x * blockDim.x + threadIdx.x; i < n4; i += stride) {
        float4 v = ((const float4*)in)[i];
        ushort4 o;
        o.x = f2bf(v.x); o.y = f2bf(v.y); o.z = f2bf(v.z); o.w = f2bf(v.w);
        ((ushort4*)out)[i] = o;
    }
}

#define GLL(gsrc, ldst) \
    __builtin_amdgcn_global_load_lds( \
        (__attribute__((address_space(1))) void*)(gsrc), \
        (__attribute__((address_space(3))) void*)(ldst), 16, 0, 0)

// ---------------- 256x256-tile bf16 GEMM, C = A * B^T (+epilogue) ----------------
// A: M x K bf16 row-major; B: N x K bf16 row-major. M%256==0, N%256==0, K%64==0,
// grid divisible by 8.
// LDS buffer (per K-tile, 64 KB): A region = 32 frag-blocks (fm 0..15 x ks 0..1)
// of 1024 B; block (fm,ks) holds lane l's bf16x8 = A[fm*16+(l&15)][ks*32+(l>>4)*8]
// at byte offset (fm*2+ks)*1024 + l*16. B region identical at +32 KB (fn over N).
// EPI 0: bf16 (acc+bias); EPI 1: bf16 silu(g)*(acc+bias); EPI 2: fp32 (acc+bias)
template<int EPI>
__global__ __launch_bounds__(512, 2)
void gemm256(const unsigned short* __restrict__ A,
             const unsigned short* __restrict__ B,
             const float* __restrict__ bias,
             const unsigned short* __restrict__ gbuf,
             void* __restrict__ Cv,
             int M, int N, int K) {
    __shared__ unsigned short lds[2 * 32768];   // 2 x 64 KB

    const int tid  = threadIdx.x;
    const int lane = tid & 63;
    const int w    = tid >> 6;       // wave 0..7
    const int wm   = w >> 2;         // 0..1  (M half, 128 rows)
    const int wn   = w & 3;          // 0..3  (N quarter, 64 cols)

    // XCD-aware bijective swizzle (grid % 8 == 0)
    const int ntn = N >> 8;
    const int chunk = gridDim.x >> 3;
    const int sw = (blockIdx.x & 7) * chunk + (blockIdx.x >> 3);
    const int bm = sw / ntn, bn = sw % ntn;

    const unsigned short* Ag = A + (size_t)(bm * 256) * K;
    const unsigned short* Bg = B + (size_t)(bn * 256) * K;

    // per-lane gather offset for staging: row (l&15), col-chunk (l>>4)*8
    const size_t gBase = (size_t)(lane & 15) * K + ((lane >> 4) << 3);
    // block j (= fm*2+ks) adds uniform (j>>1)*16*K + (j&1)*32

    // ds_read base (shorts): lane*8 within each 512-short block
    const int lofs = lane * 8;

    f32x4 acc[8][4];
#pragma unroll
    for (int m = 0; m < 8; ++m)
#pragma unroll
        for (int n = 0; n < 4; ++n)
            acc[m][n] = (f32x4){0.f, 0.f, 0.f, 0.f};

    const int NT = K >> 6;

    // ---- prologue: stage K-tile 0 into buf 0 (wave w stages blocks w*4..w*4+3) ----
#pragma unroll
    for (int i = 0; i < 4; ++i) {
        const int j = w * 4 + i;
        const size_t gc = (size_t)(j >> 1) * 16 * K + (j & 1) * 32;
        GLL(Ag + gBase + gc, lds + j * 512);
        GLL(Bg + gBase + gc, lds + 16384 + j * 512);
    }
    asm volatile("s_waitcnt vmcnt(0)" ::: "memory");
    __builtin_amdgcn_s_barrier();

#define MFMA16(MB, AF, BF) \
    { __builtin_amdgcn_s_setprio(1); \
      _Pragma("unroll") \
      for (int mi = 0; mi < 4; ++mi) { \
        _Pragma("unroll") \
        for (int n = 0; n < 4; ++n) \
            acc[(MB) + mi][n] = __builtin_amdgcn_mfma_f32_16x16x32_bf16( \
                AF[mi], BF[n], acc[(MB) + mi][n], 0, 0, 0); } \
      __builtin_amdgcn_s_setprio(0); }

    // ---- main loop: 4 drifting phases/tile, 1 vmcnt(0)+barrier per tile ----
    for (int t = 0; t < NT; ++t) {
        const unsigned short* bc = lds + (t & 1) * 32768;          // compute buf
        unsigned short* bs = lds + ((t + 1) & 1) * 32768;          // stage buf
        const int ts = (t + 1 < NT) ? (t + 1) : (NT - 1);          // clamped tail
        const unsigned short* sA = Ag + (size_t)ts * 64;
        const unsigned short* sB = Bg + (size_t)ts * 64;

        bf16x8 a_[4], b_[4];
        // ph1: read A(m0-3,ks0)+B(ks0) | stage 4 A-blocks of t+1 | 16 MFMA
#pragma unroll
        for (int mi = 0; mi < 4; ++mi)
            a_[mi] = *(const bf16x8*)(bc + ((wm * 8 + mi) * 2 + 0) * 512 + lofs);
#pragma unroll
        for (int n = 0; n < 4; ++n)
            b_[n] = *(const bf16x8*)(bc + 16384 + ((wn * 4 + n) * 2 + 0) * 512 + lofs);
#pragma unroll
        for (int i = 0; i < 4; ++i) {
            const int j = w * 4 + i;
            GLL(sA + gBase + (size_t)(j >> 1) * 16 * K + (j & 1) * 32, bs + j * 512);
        }
        MFMA16(0, a_, b_);

        // ph2: read A(m4-7,ks0) | stage 4 B-blocks of t+1 | 16 MFMA
        bf16x8 a2_[4];
#pragma unroll
        for (int mi = 0; mi < 4; ++mi)
            a2_[mi] = *(const bf16x8*)(bc + ((wm * 8 + 4 + mi) * 2 + 0) * 512 + lofs);
#pragma unroll
        for (int i = 0; i < 4; ++i) {
            const int j = w * 4 + i;
            GLL(sB + gBase + (size_t)(j >> 1) * 16 * K + (j & 1) * 32, bs + 16384 + j * 512);
        }
        MFMA16(4, a2_, b_);

        // ph3: read A(m0-3,ks1)+B(ks1) | 16 MFMA
#pragma unroll
        for (int mi = 0; mi < 4; ++mi)
            a_[mi] = *(const bf16x8*)(bc + ((wm * 8 + mi) * 2 + 1) * 512 + lofs);
#pragma unroll
        for (int n = 0; n < 4; ++n)
            b_[n] = *(const bf16x8*)(bc + 16384 + ((wn * 4 + n) * 2 + 1) * 512 + lofs);
        MFMA16(0, a_, b_);

        // ph4: read A(m4-7,ks1) | 16 MFMA
#pragma unroll
        for (int mi = 0; mi < 4; ++mi)
            a2_[mi] = *(const bf16x8*)(bc + ((wm * 8 + 4 + mi) * 2 + 1) * 512 + lofs);
        MFMA16(4, a2_, b_);

        // all 8 of my t+1 stages landed; every wave drains its own before the
        // barrier, so after it the whole t+1 buffer is valid for everyone.
        asm volatile("s_waitcnt vmcnt(0)" ::: "memory");
        __builtin_amdgcn_s_barrier();
    }
#undef MFMA16

    // ---- epilogue: C/D layout col=lane&15, row=(lane>>4)*4+j  [m89-verified] ----
    const int row0 = bm * 256 + wm * 128 + (lane >> 4) * 4;
    const int col0 = bn * 256 + wn * 64 + (lane & 15);
#pragma unroll
    for (int n = 0; n < 4; ++n) {
        const int col = col0 + n * 16;
        const float bv = bias[col];
#pragma unroll
        for (int m = 0; m < 8; ++m) {
            const int rb = row0 + m * 16;
#pragma unroll
            for (int j = 0; j < 4; ++j) {
                const size_t idx = (size_t)(rb + j) * (size_t)N + col;
                float v = acc[m][n][j] + bv;
                if (EPI == 0) {
                    ((unsigned short*)Cv)[idx] = f2bf(v);
                } else if (EPI == 1) {
                    float g = bf2f(gbuf[idx]);
                    float s = g / (1.f + __expf(-g));   // silu(g)
                    ((unsigned short*)Cv)[idx] = f2bf(s * v);
                } else {
                    ((float*)Cv)[idx] = v;
                }
            }
        }
    }
}

// ---------------- launcher ----------------
extern "C" void kernel_launch(void* const* d_in, const int* in_sizes, int n_in,
                              void* d_out, int out_size, void* d_ws, size_t ws_size,
                              hipStream_t stream) {
    const float* x  = (const float*)d_in[0];   // (2,2048,4096)
    const float* wg = (const float*)d_in[1];   // (11008,4096)
    const float* bg = (const float*)d_in[2];
    const float* wu = (const float*)d_in[3];
    const float* bu = (const float*)d_in[4];
    const float* wd = (const float*)d_in[5];   // (4096,11008)
    const float* bd = (const float*)d_in[6];

    const size_t NX = (size_t)M_TOK * HID;     // 16,777,216
    const size_t NW = (size_t)INT_ * HID;      // 45,088,768 (== M_TOK*INT_)

    unsigned short* ws = (unsigned short*)d_ws;
    unsigned short* Xb = ws;                   // x bf16
    unsigned short* S1 = Xb + NX;              // Wg -> later t
    unsigned short* S2 = S1 + NW;              // g  -> later Wd
    unsigned short* S3 = S2 + NW;              // Wu
    // peak ws need: (NX + 3*NW)*2 = 304,087,040 bytes

    dim3 blk512(512);
    dim3 blk256(256);
    const int CG = 2048;

    cvt_f32_bf16<<<CG, blk256, 0, stream>>>(x,  Xb, (int)(NX / 4));
    cvt_f32_bf16<<<CG, blk256, 0, stream>>>(wg, S1, (int)(NW / 4));
    // gate: g = x @ Wg^T + bg  (bf16 -> S2)   grid 16*43=688 (%8==0)
    gemm256<0><<<dim3(16 * 43), blk512, 0, stream>>>(Xb, S1, bg, (const unsigned short*)nullptr,
                                                     (void*)S2, M_TOK, INT_, HID);
    cvt_f32_bf16<<<CG, blk256, 0, stream>>>(wu, S3, (int)(NW / 4));
    // up + fuse: t = silu(g) * (x @ Wu^T + bu)  (bf16 -> S1, Wg dead)
    gemm256<1><<<dim3(16 * 43), blk512, 0, stream>>>(Xb, S3, bu, S2,
                                                     (void*)S1, M_TOK, INT_, HID);
    cvt_f32_bf16<<<CG, blk256, 0, stream>>>(wd, S2, (int)(NW / 4));
    // down: out = t @ Wd^T + bd  (fp32 -> d_out)  grid 16*16=256 (%8==0)
    gemm256<2><<<dim3(16 * 16), blk512, 0, stream>>>(S1, S2, bd, (const unsigned short*)nullptr,
                                                     d_out, M_TOK, HID, INT_);
}

// Round 9
// 1137.363 us; speedup vs baseline: 1.3999x; 1.3999x over previous
//
#include <hip/hip_runtime.h>
#include <hip/hip_bf16.h>

// SwiGLU MLP: out = down( silu(x@Wg^T + bg) * (x@Wu^T + bu) ) + bd
// M=4096 tokens, H=4096, I=11008. fp32 in/out, bf16 MFMA compute.
// GEMM: m201-style 8-phase schedule. 256x256 tile, BK=64, 8 waves (2Mx4N),
// 2-deep LDS dbuf (128 KiB). Per K-tile: 4 phases, each = {ds_read quadrant
// frags | stage 1 half | barrier | lgkm(0) | 16 MFMA (setprio) | barrier}.
// Counted waits vmcnt(2)@ph1 / vmcnt(4)@ph4 (derived, never drain to 0).
// Interleaved halves (A: 64-row stripes, B: 32-col stripes) make stage order
// A0,B0,B1,A1 match use order. XOR slot-swizzle (slot ^= row&7): conflict-free
// ds_read AND coalescing-preserving pre-swizzled global source (linear LDS dest).

#define M_TOK 4096
#define HID   4096
#define INT_  11008

typedef __attribute__((ext_vector_type(8))) short bf16x8;
typedef __attribute__((ext_vector_type(4))) float f32x4;

__device__ __forceinline__ unsigned short f2bf(float f) {
    union { float f; unsigned int u; } a; a.f = f;
    unsigned int u = a.u;
    u += 0x7fff + ((u >> 16) & 1);   // RNE
    return (unsigned short)(u >> 16);
}

__device__ __forceinline__ float bf2f(unsigned short h) {
    union { unsigned int u; float f; } a; a.u = ((unsigned int)h) << 16;
    return a.f;
}

// ---------------- fp32 -> bf16 convert (vectorized, grid-stride) ----------------
__global__ void cvt_f32_bf16(const float* __restrict__ in, unsigned short* __restrict__ out, int n4) {
    int stride = gridDim.x * blockDim.x;
    for (int i = blockIdx.x * blockDim.x + threadIdx.x; i < n4; i += stride) {
        float4 v = ((const float4*)in)[i];
        ushort4 o;
        o.x = f2bf(v.x); o.y = f2bf(v.y); o.z = f2bf(v.z); o.w = f2bf(v.w);
        ((ushort4*)out)[i] = o;
    }
}

#define GLL(gsrc, ldst) \
    __builtin_amdgcn_global_load_lds( \
        (__attribute__((address_space(1))) void*)(gsrc), \
        (__attribute__((address_space(3))) void*)(ldst), 16, 0, 0)

// ---------------- 256x256-tile bf16 GEMM, C = A * B^T (+epilogue) ----------------
// A: M x K bf16 row-major; B: N x K bf16 row-major. M%256==0, N%256==0, K%64==0,
// K/64 >= 2, grid divisible by 8.
// LDS per buffer (shorts): A-half0 [0,8192), A-half1 [8192,16384),
//                          B-half0 [16384,24576), B-half1 [24576,32768).
// A-half h = rows with ((row>>6)&1)==h, packed [128][64]; B-half h = N-cols with
// ((col>>5)&1)==h, packed [128][64]. Within a row, 16B slot s stored at s^(r&7).
// EPI 0: bf16 (acc+bias); EPI 1: bf16 silu(g)*(acc+bias); EPI 2: fp32 (acc+bias)
template<int EPI>
__global__ __launch_bounds__(512, 2)
void gemm256(const unsigned short* __restrict__ A,
             const unsigned short* __restrict__ B,
             const float* __restrict__ bias,
             const unsigned short* __restrict__ gbuf,
             void* __restrict__ Cv,
             int M, int N, int K) {
    __shared__ unsigned short lds[2 * 32768];   // 128 KiB

    const int tid  = threadIdx.x;
    const int lane = tid & 63;
    const int w    = tid >> 6;       // wave 0..7
    const int wm   = w >> 2;         // 0..1  (M half, 128 rows)
    const int wn   = w & 3;          // 0..3  (N quarter, 64 cols)

    // XCD-aware bijective swizzle (grid % 8 == 0)
    const int ntn = N >> 8;
    const int chunk = gridDim.x >> 3;
    const int sw = (blockIdx.x & 7) * chunk + (blockIdx.x >> 3);
    const int bm = sw / ntn, bn = sw % ntn;

    const unsigned short* Ag = A + (size_t)(bm * 256) * K;
    const unsigned short* Bg = B + (size_t)(bn * 256) * K;

    // ---- staging source offsets (pre-swizzled; LDS dest linear) ----
    // slot sigma = i*512+tid; physical slot sp -> logical s = sp ^ (r&7);
    // the 8 lanes of one row permute 16B chunks of the same 128B segment.
    int offA[2][2], offB[2][2];
#pragma unroll
    for (int h = 0; h < 2; ++h)
#pragma unroll
        for (int i = 0; i < 2; ++i) {
            int sig = i * 512 + tid;
            int r   = sig >> 3;            // packed row/col-row 0..127
            int s   = (sig & 7) ^ (r & 7); // logical 16B slot within 64-col row
            int grow = ((r >> 6) * 2 + h) * 64 + (r & 63);   // A global row
            int gcol = ((r >> 5) * 2 + h) * 32 + (r & 31);   // B global N-col
            offA[h][i] = grow * K + s * 8;
            offB[h][i] = gcol * K + s * 8;
        }

    // ---- ds_read fragment addressing (swizzled slots) ----
    const int rl = lane & 15;
    const int kg = lane >> 4;
    const int x  = rl & 7;
    // A (shorts): qm*8192 + (wm*64 + fm*16 + rl)*64 + ((ks*4+kg)^x)*8
    // B (shorts): 16384 + qn*8192 + (wn*32 + fn*16 + rl)*64 + ((ks*4+kg)^x)*8
    const int aRow = (wm * 64 + rl) * 64;
    const int bRow = 16384 + (wn * 32 + rl) * 64;
    int slt[2];
#pragma unroll
    for (int ks = 0; ks < 2; ++ks) slt[ks] = ((ks * 4 + kg) ^ x) * 8;

    f32x4 acc[2][2][8];
#pragma unroll
    for (int qm = 0; qm < 2; ++qm)
#pragma unroll
        for (int qn = 0; qn < 2; ++qn)
#pragma unroll
            for (int f = 0; f < 8; ++f)
                acc[qm][qn][f] = (f32x4){0.f, 0.f, 0.f, 0.f};

    const int NT = K >> 6;

#define STAGE_A(H, DST, SRC) \
    GLL((SRC) + offA[H][0], (DST) + (H) * 8192 + tid * 8); \
    GLL((SRC) + offA[H][1], (DST) + (H) * 8192 + 4096 + tid * 8)
#define STAGE_B(H, DST, SRC) \
    GLL((SRC) + offB[H][0], (DST) + 16384 + (H) * 8192 + tid * 8); \
    GLL((SRC) + offB[H][1], (DST) + 16384 + (H) * 8192 + 4096 + tid * 8)

    // ---- prologue: stage tile 0 (A0,B0,B1,A1), drain once ----
    {
        unsigned short* d0 = lds;
        STAGE_A(0, d0, Ag); STAGE_B(0, d0, Bg); STAGE_B(1, d0, Bg); STAGE_A(1, d0, Ag);
    }
    asm volatile("s_waitcnt vmcnt(0)" ::: "memory");
    __builtin_amdgcn_s_barrier();

#define RD_A(QM) \
    { _Pragma("unroll") for (int ks = 0; ks < 2; ++ks) \
      _Pragma("unroll") for (int fm = 0; fm < 4; ++fm) \
        aK[ks * 4 + fm] = *(const bf16x8*)(bc + (QM) * 8192 + aRow + fm * 1024 + slt[ks]); }
#define RD_B(QN, BB) \
    { _Pragma("unroll") for (int ks = 0; ks < 2; ++ks) \
      _Pragma("unroll") for (int fn = 0; fn < 2; ++fn) \
        BB[ks * 2 + fn] = *(const bf16x8*)(bc + (QN) * 8192 + bRow + fn * 1024 + slt[ks]); }
#define Q16(QM, QN, BB) \
    { __builtin_amdgcn_s_setprio(1); \
      _Pragma("unroll") for (int ks = 0; ks < 2; ++ks) \
      _Pragma("unroll") for (int fm = 0; fm < 4; ++fm) \
      _Pragma("unroll") for (int fn = 0; fn < 2; ++fn) \
        acc[QM][QN][fm * 2 + fn] = __builtin_amdgcn_mfma_f32_16x16x32_bf16( \
            aK[ks * 4 + fm], BB[ks * 2 + fn], acc[QM][QN][fm * 2 + fn], 0, 0, 0); \
      __builtin_amdgcn_s_setprio(0); }
#define LGKM0 \
    asm volatile("s_waitcnt lgkmcnt(0)" ::: "memory"); \
    __builtin_amdgcn_sched_barrier(0)

    // ---- main loop: 4 phases/K-tile (8-phase per 2 tiles) ----
    for (int t = 0; t < NT; ++t) {
        const unsigned short* bc = lds + (t & 1) * 32768;
        unsigned short* sb = lds + ((t + 1) & 1) * 32768;
        const int ts = (t + 1 < NT) ? (t + 1) : (NT - 1);   // clamped tail re-stage
        const unsigned short* sAt = Ag + (size_t)ts * 64;
        const unsigned short* sBt = Bg + (size_t)ts * 64;

        bf16x8 aK[8], b0[4], b1[4];

        // ph1: read A(q_m=0) + B(q_n=0) | stage A0(t+1) | Q(0,0) | vmcnt(2)
        RD_A(0); RD_B(0, b0);
        STAGE_A(0, sb, sAt);
        __builtin_amdgcn_s_barrier();
        LGKM0;
        Q16(0, 0, b0);
        asm volatile("s_waitcnt vmcnt(2)" ::: "memory");   // B1(t),A1(t) landed
        __builtin_amdgcn_s_barrier();

        // ph2: read B(q_n=1) | stage B0(t+1) | Q(0,1)
        RD_B(1, b1);
        STAGE_B(0, sb, sBt);
        __builtin_amdgcn_s_barrier();
        LGKM0;
        Q16(0, 1, b1);
        __builtin_amdgcn_s_barrier();

        // ph3: read A(q_m=1) | stage B1(t+1) | Q(1,1)
        RD_A(1);
        STAGE_B(1, sb, sBt);
        __builtin_amdgcn_s_barrier();
        LGKM0;
        Q16(1, 1, b1);
        __builtin_amdgcn_s_barrier();

        // ph4: (no reads) | stage A1(t+1) | Q(1,0) | vmcnt(4)
        STAGE_A(1, sb, sAt);
        __builtin_amdgcn_s_barrier();
        Q16(1, 0, b0);
        asm volatile("s_waitcnt vmcnt(4)" ::: "memory");   // A0(t+1),B0(t+1) landed
        __builtin_amdgcn_s_barrier();
    }
#undef RD_A
#undef RD_B
#undef Q16
#undef LGKM0
#undef STAGE_A
#undef STAGE_B

    // ---- epilogue: C/D layout col=lane&15, row=(lane>>4)*4+j  [m89-verified] ----
    const int rbase = bm * 256 + wm * 128 + (lane >> 4) * 4;
    const int cbase = bn * 256 + wn * 64 + (lane & 15);
#pragma unroll
    for (int qm = 0; qm < 2; ++qm)
#pragma unroll
        for (int qn = 0; qn < 2; ++qn)
#pragma unroll
            for (int fn = 0; fn < 2; ++fn) {
                const int col = cbase + qn * 32 + fn * 16;
                const float bv = bias[col];
#pragma unroll
                for (int fm = 0; fm < 4; ++fm) {
                    const int rb = rbase + qm * 64 + fm * 16;
#pragma unroll
                    for (int j = 0; j < 4; ++j) {
                        const size_t idx = (size_t)(rb + j) * (size_t)N + col;
                        float v = acc[qm][qn][fm * 2 + fn][j] + bv;
                        if (EPI == 0) {
                            ((unsigned short*)Cv)[idx] = f2bf(v);
                        } else if (EPI == 1) {
                            float g = bf2f(gbuf[idx]);
                            float s = g / (1.f + __expf(-g));   // silu(g)
                            ((unsigned short*)Cv)[idx] = f2bf(s * v);
                        } else {
                            ((float*)Cv)[idx] = v;
                        }
                    }
                }
            }
}

// ---------------- launcher ----------------
extern "C" void kernel_launch(void* const* d_in, const int* in_sizes, int n_in,
                              void* d_out, int out_size, void* d_ws, size_t ws_size,
                              hipStream_t stream) {
    const float* x  = (const float*)d_in[0];   // (2,2048,4096)
    const float* wg = (const float*)d_in[1];   // (11008,4096)
    const float* bg = (const float*)d_in[2];
    const float* wu = (const float*)d_in[3];
    const float* bu = (const float*)d_in[4];
    const float* wd = (const float*)d_in[5];   // (4096,11008)
    const float* bd = (const float*)d_in[6];

    const size_t NX = (size_t)M_TOK * HID;     // 16,777,216
    const size_t NW = (size_t)INT_ * HID;      // 45,088,768 (== M_TOK*INT_)

    unsigned short* ws = (unsigned short*)d_ws;
    unsigned short* Xb = ws;                   // x bf16
    unsigned short* S1 = Xb + NX;              // Wg -> later t
    unsigned short* S2 = S1 + NW;              // g  -> later Wd
    unsigned short* S3 = S2 + NW;              // Wu
    // peak ws need: (NX + 3*NW)*2 = 304,087,040 bytes

    dim3 blk512(512);
    dim3 blk256(256);
    const int CG = 2048;

    cvt_f32_bf16<<<CG, blk256, 0, stream>>>(x,  Xb, (int)(NX / 4));
    cvt_f32_bf16<<<CG, blk256, 0, stream>>>(wg, S1, (int)(NW / 4));
    // gate: g = x @ Wg^T + bg  (bf16 -> S2)   grid 16*43=688 (%8==0)
    gemm256<0><<<dim3(16 * 43), blk512, 0, stream>>>(Xb, S1, bg, (const unsigned short*)nullptr,
                                                     (void*)S2, M_TOK, INT_, HID);
    cvt_f32_bf16<<<CG, blk256, 0, stream>>>(wu, S3, (int)(NW / 4));
    // up + fuse: t = silu(g) * (x @ Wu^T + bu)  (bf16 -> S1, Wg dead)
    gemm256<1><<<dim3(16 * 43), blk512, 0, stream>>>(Xb, S3, bu, S2,
                                                     (void*)S1, M_TOK, INT_, HID);
    cvt_f32_bf16<<<CG, blk256, 0, stream>>>(wd, S2, (int)(NW / 4));
    // down: out = t @ Wd^T + bd  (fp32 -> d_out)  grid 16*16=256 (%8==0), NT=172
    gemm256<2><<<dim3(16 * 16), blk512, 0, stream>>>(S1, S2, bd, (const unsigned short*)nullptr,
                                                     d_out, M_TOK, HID, INT_);
}